// Round 3
// baseline (151.831 us; speedup 1.0000x reference)
//
#include <hip/hip_runtime.h>

typedef unsigned short ushort_t;

#define LL 8192
#define TT 32
#define NBATCH 8
#define NGPB 2047                  // 4-sample groups per batch (2047*4 = 8188)
#define NGROUPS (NBATCH * NGPB)    // 16376
#define NSAMP 65504                // samples per track = NGROUPS*4
#define KSTRIDE 65536              // padded per-track key stride (ushorts)
#define NBINS 1000

#define WS_CAP 4096
#define WS_KEYS_BYTE_OFF 32768
#define WS_NEEDED (WS_KEYS_BYTE_OFF + (size_t)TT * KSTRIDE * 2)

#define MARG_COV 136
#define MSTRIDE 273                // 2*136 + 1 pad (odd -> bank spread)
#define ROWS 16                    // joint rows per K2 block

__device__ __forceinline__ int bin_of(float v) {
    v = fminf(fmaxf(v, 0.0f), 10.0f);
    int b = (int)ceilf(v * 100.0f) - 1;
    b = b < 0 ? 0 : b;
    return b > (NBINS - 1) ? (NBINS - 1) : b;
}

// ---------------- K0: zero marginals + overflow counter ----------------
__global__ __launch_bounds__(256) void k0_zero(int* __restrict__ out, int* __restrict__ ws_cnt) {
    const int i = blockIdx.x * 256 + threadIdx.x;
    if (i < 2 * TT * NBINS) out[i] = 0;
    if (i == 0) *ws_cnt = 0;
}

// ---------------- K1: bin samples -> 16-bit keys + marginals ----------------
__global__ __launch_bounds__(512) void k1_bin(
    const float* __restrict__ yp, const float* __restrict__ yt,
    int* __restrict__ out, ushort_t* __restrict__ keys,
    int* __restrict__ ws_cnt, int* __restrict__ ws_rec)
{
    __shared__ int s_m[TT * MSTRIDE];
    const int tid = threadIdx.x;
    const int trk = tid & 31;         // lane-fast -> coalesced input loads
    const int slotg = tid >> 5;       // 0..15

    for (int i = tid; i < TT * MSTRIDE; i += 512) s_m[i] = 0;
    __syncthreads();

    int* __restrict__ marg   = &s_m[trk * MSTRIDE];   // [0,136)=pred, [136,272)=targ
    int* __restrict__ pred_g = out;
    int* __restrict__ targ_g = out + TT * NBINS;

    int cp0 = 0, ct0 = 0;

    #pragma unroll
    for (int pass = 0; pass < 2; ++pass) {
        const int g = blockIdx.x * 32 + pass * 16 + slotg;
        if (g >= NGROUPS) continue;
        const int b = g / NGPB;
        const int j = g - b * NGPB;
        const int n0 = g * 4;                                   // global sample idx base
        const size_t base = ((size_t)b * LL + 4 * (size_t)j) * TT + trk;
        float xp[8], xt[8];
        #pragma unroll
        for (int k = 0; k < 8; ++k) {
            xp[k] = yp[base + (size_t)k * TT];
            xt[k] = yt[base + (size_t)k * TT];
        }
        ushort_t kk[4];
        #pragma unroll
        for (int r = 0; r < 4; ++r) {
            const float ps = (xp[r]+xp[r+1]+xp[r+2]+xp[r+3]+xp[r+4]) * 0.2f;
            const float ts = (xt[r]+xt[r+1]+xt[r+2]+xt[r+3]+xt[r+4]) * 0.2f;
            int key = 0xFFFF;                                   // escape / invalid
            if (isfinite(ps) && isfinite(ts)) {
                const int pb = bin_of(ps);
                const int tb = bin_of(ts);
                if (pb < 255 && tb < 255) {
                    key = (pb << 8) | tb;
                } else {
                    const int idx = atomicAdd(ws_cnt, 1);
                    if (idx < WS_CAP) ws_rec[idx] = (trk << 20) | (pb << 10) | tb;
                }
                if (pb == 0)             cp0++;
                else if (pb < MARG_COV)  atomicAdd(&marg[pb], 1);
                else                     atomicAdd(&pred_g[trk * NBINS + pb], 1);
                if (tb == 0)             ct0++;
                else if (tb < MARG_COV)  atomicAdd(&marg[MARG_COV + tb], 1);
                else                     atomicAdd(&targ_g[trk * NBINS + tb], 1);
            }
            kk[r] = (ushort_t)key;
        }
        *(ushort4*)&keys[(size_t)trk * KSTRIDE + n0] =
            make_ushort4(kk[0], kk[1], kk[2], kk[3]);
    }

    if (cp0) atomicAdd(&marg[0], cp0);
    if (ct0) atomicAdd(&marg[MARG_COV], ct0);
    __syncthreads();

    for (int i = tid; i < TT * (2 * MARG_COV); i += 512) {
        const int tr = i / (2 * MARG_COV);
        const int sl = i - tr * (2 * MARG_COV);
        const int c  = s_m[tr * MSTRIDE + sl];
        if (!c) continue;
        if (sl < MARG_COV) atomicAdd(&pred_g[tr * NBINS + sl], c);
        else               atomicAdd(&targ_g[tr * NBINS + (sl - MARG_COV)], c);
    }
}

// ---------------- K2: per (track, 16-row range) joint tile, plain stores ----------------
__global__ __launch_bounds__(512) void k2_joint(
    const ushort_t* __restrict__ keys, int* __restrict__ joint_g,
    const int* __restrict__ ws_cnt, const int* __restrict__ ws_rec)
{
    __shared__ int hist[ROWS * NBINS];                 // 64,000 B
    const int tid  = threadIdx.x;
    const int t    = blockIdx.x;                       // track fastest -> XCD key locality
    const int r0   = blockIdx.y * ROWS;
    const int rows = (NBINS - r0) < ROWS ? (NBINS - r0) : ROWS;

    for (int i = tid; i < ROWS * NBINS; i += 512) hist[i] = 0;
    __syncthreads();

    const ushort_t* __restrict__ kt = keys + (size_t)t * KSTRIDE;
    int c00 = 0;

    #pragma unroll 4
    for (int p = 0; p < 16; ++p) {
        const int i8 = tid + p * 512;                  // uint4 = 8 keys
        if (i8 < NSAMP / 8) {
            const uint4 w = *(const uint4*)&kt[i8 * 8];
            const unsigned dw[4] = {w.x, w.y, w.z, w.w};
            #pragma unroll
            for (int h = 0; h < 4; ++h) {
                const unsigned lo = dw[h] & 0xFFFFu;
                const unsigned hi = dw[h] >> 16;
                if (lo == 0u) c00++;
                else if (lo != 0xFFFFu) {
                    const unsigned rr = (lo >> 8) - (unsigned)r0;
                    if (rr < (unsigned)rows) atomicAdd(&hist[rr * NBINS + (lo & 255u)], 1);
                }
                if (hi == 0u) c00++;
                else if (hi != 0xFFFFu) {
                    const unsigned rr = (hi >> 8) - (unsigned)r0;
                    if (rr < (unsigned)rows) atomicAdd(&hist[rr * NBINS + (hi & 255u)], 1);
                }
            }
        }
    }

    if (r0 == 0 && c00) atomicAdd(&hist[0], c00);

    const int cnt = min(*ws_cnt, WS_CAP);
    for (int i = tid; i < cnt; i += 512) {
        const int rec = ws_rec[i];
        const int rt  = rec >> 20;
        const int rpb = (rec >> 10) & 1023;
        const int rtb = rec & 1023;
        const unsigned rr = (unsigned)(rpb - r0);
        if (rt == t && rr < (unsigned)rows) atomicAdd(&hist[rr * NBINS + rtb], 1);
    }
    __syncthreads();

    int* __restrict__ dst = joint_g + (size_t)t * (NBINS * NBINS) + r0 * NBINS;
    const int n4 = rows * NBINS / 4;
    for (int i = tid; i < n4; i += 512)
        ((int4*)dst)[i] = ((const int4*)hist)[i];
}

// ---------------- fallback (proven round-2 path) if ws too small ----------------
__global__ __launch_bounds__(256) void fb_zero(int4* __restrict__ p, int n4) {
    const int i = blockIdx.x * 256 + threadIdx.x;
    if (i < n4) p[i] = make_int4(0, 0, 0, 0);
}

__global__ __launch_bounds__(512) void fb_hist(
    const float* __restrict__ yp, const float* __restrict__ yt,
    int* __restrict__ out)
{
    __shared__ int s_h[16 * 1009];
    const int tid = threadIdx.x;
    const int trk = tid & 15;
    const int slot = tid >> 4;
    const int t = blockIdx.y * 16 + trk;

    for (int i = tid; i < 16 * 1009; i += 512) s_h[i] = 0;
    __syncthreads();
    int* __restrict__ reg = &s_h[trk * 1009];
    int* __restrict__ pred_g  = out;
    int* __restrict__ targ_g  = out + TT * NBINS;
    int* __restrict__ joint_g = out + 2 * TT * NBINS;
    int* __restrict__ joint_t = joint_g + (size_t)t * NBINS * NBINS;
    int c00 = 0, cp0 = 0, ct0 = 0;
    const int g0 = blockIdx.x * 128;
    #pragma unroll
    for (int pass = 0; pass < 4; ++pass) {
        const int g = g0 + pass * 32 + slot;
        if (g < NGROUPS) {
            const int b = g / NGPB;
            const int j = g - b * NGPB;
            const size_t base = ((size_t)b * LL + 4 * (size_t)j) * TT + t;
            float xp[8], xt[8];
            #pragma unroll
            for (int k = 0; k < 8; ++k) {
                xp[k] = yp[base + (size_t)k * TT];
                xt[k] = yt[base + (size_t)k * TT];
            }
            #pragma unroll
            for (int r = 0; r < 4; ++r) {
                const float ps = (xp[r]+xp[r+1]+xp[r+2]+xp[r+3]+xp[r+4]) * 0.2f;
                const float ts = (xt[r]+xt[r+1]+xt[r+2]+xt[r+3]+xt[r+4]) * 0.2f;
                if (!(isfinite(ps) && isfinite(ts))) continue;
                const int pb = bin_of(ps);
                const int tb = bin_of(ts);
                if (pb == 0) cp0++;
                else if (pb < 136) atomicAdd(&reg[736 + pb], 1);
                else atomicAdd(&pred_g[t * NBINS + pb], 1);
                if (tb == 0) ct0++;
                else if (tb < 136) atomicAdd(&reg[872 + tb], 1);
                else atomicAdd(&targ_g[t * NBINS + tb], 1);
                if (pb == 0 && tb == 0) c00++;
                else if (pb < 16 && tb < 16) atomicAdd(&reg[pb * 16 + tb], 1);
                else if (pb == 0 && tb < 256) atomicAdd(&reg[256 + tb - 16], 1);
                else if (tb == 0 && pb < 256) atomicAdd(&reg[496 + pb - 16], 1);
                else atomicAdd(&joint_t[pb * NBINS + tb], 1);
            }
        }
    }
    if (c00) atomicAdd(&reg[0],   c00);
    if (cp0) atomicAdd(&reg[736], cp0);
    if (ct0) atomicAdd(&reg[872], ct0);
    __syncthreads();
    const int h0 = blockIdx.y * 16;
    for (int i = tid; i < 16 * 1008; i += 512) {
        const int tr = i / 1008;
        const int sl = i - tr * 1008;
        const int c  = s_h[tr * 1009 + sl];
        if (c == 0) continue;
        const int tg = h0 + tr;
        if (sl < 256) atomicAdd(&joint_g[(size_t)tg * NBINS * NBINS + (sl >> 4) * NBINS + (sl & 15)], c);
        else if (sl < 496) atomicAdd(&joint_g[(size_t)tg * NBINS * NBINS + (sl - 240)], c);
        else if (sl < 736) atomicAdd(&joint_g[(size_t)tg * NBINS * NBINS + (size_t)(sl - 480) * NBINS], c);
        else if (sl < 872) atomicAdd(&pred_g[tg * NBINS + (sl - 736)], c);
        else atomicAdd(&targ_g[tg * NBINS + (sl - 872)], c);
    }
}

extern "C" void kernel_launch(void* const* d_in, const int* in_sizes, int n_in,
                              void* d_out, int out_size, void* d_ws, size_t ws_size,
                              hipStream_t stream) {
    const float* yp = (const float*)d_in[0];
    const float* yt = (const float*)d_in[1];
    int* out = (int*)d_out;

    if (ws_size >= WS_NEEDED) {
        int* ws_cnt = (int*)d_ws;
        int* ws_rec = ws_cnt + 4;
        ushort_t* keys = (ushort_t*)((char*)d_ws + WS_KEYS_BYTE_OFF);

        k0_zero<<<(2 * TT * NBINS + 255) / 256, 256, 0, stream>>>(out, ws_cnt);
        k1_bin<<<512, 512, 0, stream>>>(yp, yt, out, keys, ws_cnt, ws_rec);
        dim3 g2(TT, (NBINS + ROWS - 1) / ROWS);   // (32, 63), track fastest
        k2_joint<<<g2, 512, 0, stream>>>(keys, out + 2 * TT * NBINS, ws_cnt, ws_rec);
    } else {
        const int n4 = out_size / 4;
        fb_zero<<<(n4 + 255) / 256, 256, 0, stream>>>((int4*)out, n4);
        dim3 grid((NGROUPS + 127) / 128, 2);
        fb_hist<<<grid, 512, 0, stream>>>(yp, yt, out);
    }
}

// Round 4
// 54.022 us; speedup vs baseline: 2.8105x; 2.8105x over previous
//
#include <hip/hip_runtime.h>

typedef unsigned int uint_t;

#define LL 8192
#define TT 32
#define NBATCH 8
#define NGPB 2047                  // 4-sample groups per batch (2047*4 = 8188)
#define NGROUPS (NBATCH * NGPB)    // 16376
#define NSAMP 65504                // samples per track
#define KSTRIDE 65536              // per-track key stride (uints)
#define NBINS 1000
#define BIN_BLOCKS 512
#define HSTRIDE 260                // LDS row stride (ints): 16B-aligned rows, bank=(4r+c)&31
#define WS_NEEDED ((size_t)TT * KSTRIDE * 4)

__device__ __forceinline__ int bin_of(float v) {
    v = fminf(fmaxf(v, 0.0f), 10.0f);
    int b = (int)ceilf(v * 100.0f) - 1;
    b = b < 0 ? 0 : b;
    return b > (NBINS - 1) ? (NBINS - 1) : b;
}

// ---- ZB: fused {bin -> 32-bit keys} + {zero 128MB output} ----
__global__ __launch_bounds__(512) void zb_kernel(
    const float* __restrict__ yp, const float* __restrict__ yt,
    int4* __restrict__ out4, int n4, uint_t* __restrict__ keys)
{
    const int bid = blockIdx.x;
    const int tid = threadIdx.x;

    if (bid < BIN_BLOCKS) {
        const int trk   = tid & 31;          // lane-fast -> coalesced input loads
        const int slotg = tid >> 5;          // 0..15
        #pragma unroll
        for (int pass = 0; pass < 2; ++pass) {
            const int g = bid * 32 + pass * 16 + slotg;
            if (g >= NGROUPS) continue;
            const int b = g / NGPB;
            const int j = g - b * NGPB;
            const size_t base = ((size_t)b * LL + 4 * (size_t)j) * TT + trk;
            float xp[8], xt[8];
            #pragma unroll
            for (int k = 0; k < 8; ++k) {
                xp[k] = yp[base + (size_t)k * TT];
                xt[k] = yt[base + (size_t)k * TT];
            }
            uint_t kk[4];
            #pragma unroll
            for (int r = 0; r < 4; ++r) {
                const float ps = (xp[r]+xp[r+1]+xp[r+2]+xp[r+3]+xp[r+4]) * 0.2f;
                const float ts = (xt[r]+xt[r+1]+xt[r+2]+xt[r+3]+xt[r+4]) * 0.2f;
                uint_t key = 0xFFFFFFFFu;     // invalid marker
                if (isfinite(ps) && isfinite(ts))
                    key = ((uint_t)bin_of(ps) << 10) | (uint_t)bin_of(ts);
                kk[r] = key;
            }
            *(uint4*)&keys[(size_t)trk * KSTRIDE + (size_t)g * 4] =
                make_uint4(kk[0], kk[1], kk[2], kk[3]);
        }
    } else {
        const int i = (bid - BIN_BLOCKS) * 512 + tid;
        if (i < n4) out4[i] = make_int4(0, 0, 0, 0);
    }
}

// ---- K2: per (track, 64-row quarter): LDS hist -> plain stores + derived marginals ----
__global__ __launch_bounds__(512) void k2_kernel(
    const uint_t* __restrict__ keys, int* __restrict__ out)
{
    extern __shared__ int hist[];            // 64 * HSTRIDE ints (66,560 B)
    const int tid = threadIdx.x;
    const int t   = blockIdx.x;              // track fastest -> spread across XCDs
    const int q   = blockIdx.y;              // row quarter
    const int r0  = q * 64;

    int* __restrict__ pred_g  = out;
    int* __restrict__ targ_g  = out + TT * NBINS;
    int* __restrict__ joint_t = out + 2 * TT * NBINS + (size_t)t * NBINS * NBINS;

    for (int i = tid; i < 64 * HSTRIDE; i += 512) hist[i] = 0;
    __syncthreads();

    const uint_t* __restrict__ kt = keys + (size_t)t * KSTRIDE;
    int c00 = 0;

    #pragma unroll 4
    for (int p = 0; p < 32; ++p) {
        const int i4 = tid + p * 512;        // uint4 = 4 keys
        if (i4 < NSAMP / 4) {
            const uint4 w = *(const uint4*)&kt[i4 * 4];
            const uint_t ks[4] = {w.x, w.y, w.z, w.w};
            #pragma unroll
            for (int h = 0; h < 4; ++h) {
                const uint_t key = ks[h];
                if (key == 0xFFFFFFFFu) continue;
                const uint_t pb = key >> 10;
                const uint_t tb = key & 1023u;
                const uint_t rr = pb - (uint_t)r0;
                if (rr < 64u) {
                    if (key == 0u)          c00++;               // hot (0,0), q==0 only
                    else if (tb < 256u)     atomicAdd(&hist[rr * HSTRIDE + tb], 1);
                    else {                                       // in-row, col outside square (rare)
                        atomicAdd(&hist[rr * HSTRIDE + 256], 1); // row-extra for pred
                        atomicAdd(&joint_t[pb * NBINS + tb], 1);
                        atomicAdd(&targ_g[t * NBINS + tb], 1);
                    }
                } else if (pb >= 256u && q == 3) {               // row outside square (rare)
                    atomicAdd(&joint_t[pb * NBINS + tb], 1);
                    atomicAdd(&pred_g[t * NBINS + pb], 1);
                    atomicAdd(&targ_g[t * NBINS + tb], 1);
                }
            }
        }
    }

    if (c00) atomicAdd(&hist[0], c00);
    __syncthreads();

    // joint tile: plain int4 stores (overwrites ZB zeros)
    for (int i = tid; i < 64 * 64; i += 512) {
        const int r  = i >> 6;
        const int c4 = i & 63;
        *(int4*)&joint_t[(size_t)(r0 + r) * NBINS + c4 * 4] =
            *(const int4*)&hist[r * HSTRIDE + c4 * 4];
    }

    // pred marginal = row sums (rotated reads -> 2-way banks; 8-lane shfl reduce)
    {
        const int r = tid >> 3, s = tid & 7;
        int sum = 0;
        #pragma unroll
        for (int k = 0; k < 32; ++k)
            sum += hist[r * HSTRIDE + s * 32 + ((k + tid) & 31)];
        sum += __shfl_xor(sum, 1);
        sum += __shfl_xor(sum, 2);
        sum += __shfl_xor(sum, 4);
        if (s == 0) pred_g[t * NBINS + r0 + r] = sum + hist[r * HSTRIDE + 256];
    }

    // targ marginal partial = col sums (2 threads/col, pair reduce, atomic)
    {
        const int c = tid >> 1, u = tid & 1;
        int sum = 0;
        #pragma unroll
        for (int r = 0; r < 32; ++r)
            sum += hist[(u * 32 + r) * HSTRIDE + c];
        sum += __shfl_xor(sum, 1);
        if (u == 0 && sum) atomicAdd(&targ_g[t * NBINS + c], sum);
    }
}

// ---------------- fallback (proven round-2 path) if ws too small ----------------
__global__ __launch_bounds__(256) void fb_zero(int4* __restrict__ p, int n4) {
    const int i = blockIdx.x * 256 + threadIdx.x;
    if (i < n4) p[i] = make_int4(0, 0, 0, 0);
}

__global__ __launch_bounds__(512) void fb_hist(
    const float* __restrict__ yp, const float* __restrict__ yt,
    int* __restrict__ out)
{
    __shared__ int s_h[16 * 1009];
    const int tid = threadIdx.x;
    const int trk = tid & 15;
    const int slot = tid >> 4;
    const int t = blockIdx.y * 16 + trk;

    for (int i = tid; i < 16 * 1009; i += 512) s_h[i] = 0;
    __syncthreads();
    int* __restrict__ reg = &s_h[trk * 1009];
    int* __restrict__ pred_g  = out;
    int* __restrict__ targ_g  = out + TT * NBINS;
    int* __restrict__ joint_g = out + 2 * TT * NBINS;
    int* __restrict__ joint_t = joint_g + (size_t)t * NBINS * NBINS;
    int c00 = 0, cp0 = 0, ct0 = 0;
    const int g0 = blockIdx.x * 128;
    #pragma unroll
    for (int pass = 0; pass < 4; ++pass) {
        const int g = g0 + pass * 32 + slot;
        if (g < NGROUPS) {
            const int b = g / NGPB;
            const int j = g - b * NGPB;
            const size_t base = ((size_t)b * LL + 4 * (size_t)j) * TT + t;
            float xp[8], xt[8];
            #pragma unroll
            for (int k = 0; k < 8; ++k) {
                xp[k] = yp[base + (size_t)k * TT];
                xt[k] = yt[base + (size_t)k * TT];
            }
            #pragma unroll
            for (int r = 0; r < 4; ++r) {
                const float ps = (xp[r]+xp[r+1]+xp[r+2]+xp[r+3]+xp[r+4]) * 0.2f;
                const float ts = (xt[r]+xt[r+1]+xt[r+2]+xt[r+3]+xt[r+4]) * 0.2f;
                if (!(isfinite(ps) && isfinite(ts))) continue;
                const int pb = bin_of(ps);
                const int tb = bin_of(ts);
                if (pb == 0) cp0++;
                else if (pb < 136) atomicAdd(&reg[736 + pb], 1);
                else atomicAdd(&pred_g[t * NBINS + pb], 1);
                if (tb == 0) ct0++;
                else if (tb < 136) atomicAdd(&reg[872 + tb], 1);
                else atomicAdd(&targ_g[t * NBINS + tb], 1);
                if (pb == 0 && tb == 0) c00++;
                else if (pb < 16 && tb < 16) atomicAdd(&reg[pb * 16 + tb], 1);
                else if (pb == 0 && tb < 256) atomicAdd(&reg[256 + tb - 16], 1);
                else if (tb == 0 && pb < 256) atomicAdd(&reg[496 + pb - 16], 1);
                else atomicAdd(&joint_t[pb * NBINS + tb], 1);
            }
        }
    }
    if (c00) atomicAdd(&reg[0],   c00);
    if (cp0) atomicAdd(&reg[736], cp0);
    if (ct0) atomicAdd(&reg[872], ct0);
    __syncthreads();
    const int h0 = blockIdx.y * 16;
    for (int i = tid; i < 16 * 1008; i += 512) {
        const int tr = i / 1008;
        const int sl = i - tr * 1008;
        const int c  = s_h[tr * 1009 + sl];
        if (c == 0) continue;
        const int tg = h0 + tr;
        if (sl < 256) atomicAdd(&joint_g[(size_t)tg * NBINS * NBINS + (sl >> 4) * NBINS + (sl & 15)], c);
        else if (sl < 496) atomicAdd(&joint_g[(size_t)tg * NBINS * NBINS + (sl - 240)], c);
        else if (sl < 736) atomicAdd(&joint_g[(size_t)tg * NBINS * NBINS + (size_t)(sl - 480) * NBINS], c);
        else if (sl < 872) atomicAdd(&pred_g[tg * NBINS + (sl - 736)], c);
        else atomicAdd(&targ_g[tg * NBINS + (sl - 872)], c);
    }
}

extern "C" void kernel_launch(void* const* d_in, const int* in_sizes, int n_in,
                              void* d_out, int out_size, void* d_ws, size_t ws_size,
                              hipStream_t stream) {
    const float* yp = (const float*)d_in[0];
    const float* yt = (const float*)d_in[1];
    int* out = (int*)d_out;

    if (ws_size >= WS_NEEDED) {
        uint_t* keys = (uint_t*)d_ws;
        const int n4 = out_size / 4;                       // 8,016,000
        const int zblocks = (n4 + 511) / 512;
        zb_kernel<<<BIN_BLOCKS + zblocks, 512, 0, stream>>>(yp, yt, (int4*)out, n4, keys);
        dim3 g2(TT, 4);                                    // (track, row-quarter)
        k2_kernel<<<g2, 512, 64 * HSTRIDE * sizeof(int), stream>>>(keys, out);
    } else {
        const int n4 = out_size / 4;
        fb_zero<<<(n4 + 255) / 256, 256, 0, stream>>>((int4*)out, n4);
        dim3 grid((NGROUPS + 127) / 128, 2);
        fb_hist<<<grid, 512, 0, stream>>>(yp, yt, out);
    }
}

// Round 5
// 40.305 us; speedup vs baseline: 3.7670x; 1.3403x over previous
//
#include <hip/hip_runtime.h>

typedef unsigned int uint_t;

#define LL 8192
#define TT 32
#define NGPB 2047                    // 4-sample groups per batch
#define NGROUPS (8 * NGPB)           // 16376
#define NSAMP 65504                  // samples per track
#define KSTRIDE 65536                // per-track key stride (uints)
#define NBINS 1000
#define K1_BLOCKS 512
#define OV_CAP 8                     // overflow records per K1 block
#define HSTRIDE 260                  // LDS row stride (ints)
#define NHIST 128                    // hist blocks in K2 (32 tracks x 4 quarters)
#define NZERO 1920                   // zero blocks in K2
#define REGION_A 5952000             // int4s: rows 256..999, all tracks
#define REGION_TOT 7475712           // + rows 0..255 x cols 256..999
// ws layout (ints): [0,512) overflow counts; [512, 512+512*8) records; keys @ 64KB
#define WS_CNT_OFF 0
#define WS_REC_OFF 512
#define WS_KEYS_INT_OFF 16384
#define WS_NEEDED ((size_t)(WS_KEYS_INT_OFF + (size_t)TT * KSTRIDE) * 4)

__device__ __forceinline__ int bin_of(float v) {
    v = fminf(fmaxf(v, 0.0f), 10.0f);
    int b = (int)ceilf(v * 100.0f) - 1;
    b = b < 0 ? 0 : b;
    return b > (NBINS - 1) ? (NBINS - 1) : b;
}

// ---- K1: bin -> keys; zero marginals; record rare out-of-square samples ----
__global__ __launch_bounds__(512) void k1_bin(
    const float* __restrict__ yp, const float* __restrict__ yt,
    int* __restrict__ out, int* __restrict__ ws)
{
    __shared__ int s_ovc;
    const int tid = threadIdx.x;
    const int bid = blockIdx.x;
    if (tid == 0) s_ovc = 0;

    // zero marginal slice: 64,000 ints over 512 blocks
    if (tid < 125) out[bid * 125 + tid] = 0;
    __syncthreads();

    uint_t* __restrict__ keys = (uint_t*)(ws + WS_KEYS_INT_OFF);
    const int trk   = tid & 31;
    const int slotg = tid >> 5;

    #pragma unroll
    for (int pass = 0; pass < 2; ++pass) {
        const int g = bid * 32 + pass * 16 + slotg;
        if (g >= NGROUPS) continue;
        const int b = g / NGPB;
        const int j = g - b * NGPB;
        const size_t base = ((size_t)b * LL + 4 * (size_t)j) * TT + trk;
        float xp[8], xt[8];
        #pragma unroll
        for (int k = 0; k < 8; ++k) {
            xp[k] = yp[base + (size_t)k * TT];
            xt[k] = yt[base + (size_t)k * TT];
        }
        uint_t kk[4];
        #pragma unroll
        for (int r = 0; r < 4; ++r) {
            const float ps = (xp[r]+xp[r+1]+xp[r+2]+xp[r+3]+xp[r+4]) * 0.2f;
            const float ts = (xt[r]+xt[r+1]+xt[r+2]+xt[r+3]+xt[r+4]) * 0.2f;
            uint_t key = 0xFFFFFFFFu;
            if (isfinite(ps) && isfinite(ts)) {
                const int pb = bin_of(ps);
                const int tb = bin_of(ts);
                key = ((uint_t)pb << 10) | (uint_t)tb;
                if (pb >= 256 || tb >= 256) {
                    const int idx = atomicAdd(&s_ovc, 1);
                    if (idx < OV_CAP)
                        ws[WS_REC_OFF + bid * OV_CAP + idx] = (trk << 20) | (pb << 10) | tb;
                }
            }
            kk[r] = key;
        }
        *(uint4*)&keys[(size_t)trk * KSTRIDE + (size_t)g * 4] =
            make_uint4(kk[0], kk[1], kk[2], kk[3]);
    }

    __syncthreads();
    if (tid == 0) ws[WS_CNT_OFF + bid] = min(s_ovc, OV_CAP);
}

// ---- K2: fused {square hist tiles + marginals} || {zero out-of-square joint} ----
__global__ __launch_bounds__(512) void k2_main(
    const int* __restrict__ ws, int* __restrict__ out)
{
    extern __shared__ int hist[];                 // 64 * HSTRIDE ints
    const int tid = threadIdx.x;
    const int bid = blockIdx.x;

    int* __restrict__ pred_g  = out;
    int* __restrict__ targ_g  = out + TT * NBINS;
    int* __restrict__ joint_g = out + 2 * TT * NBINS;

    if (bid < NHIST) {
        const int t  = bid & 31;
        const int q  = bid >> 5;
        const int r0 = q * 64;
        int* __restrict__ joint_t = joint_g + (size_t)t * NBINS * NBINS;
        const uint_t* __restrict__ kt =
            (const uint_t*)(ws + WS_KEYS_INT_OFF) + (size_t)t * KSTRIDE;

        for (int i = tid; i < 64 * HSTRIDE; i += 512) hist[i] = 0;
        __syncthreads();

        int c00 = 0;
        #pragma unroll 4
        for (int p = 0; p < 32; ++p) {
            const int i4 = tid + p * 512;
            if (i4 < NGROUPS) {
                const uint4 w = *(const uint4*)&kt[i4 * 4];
                const uint_t ks[4] = {w.x, w.y, w.z, w.w};
                #pragma unroll
                for (int h = 0; h < 4; ++h) {
                    const uint_t key = ks[h];
                    const uint_t tb  = key & 1023u;
                    const uint_t rr  = (key >> 10) - (uint_t)r0;
                    if (rr < 64u && tb < 256u) {
                        if (key == 0u) c00++;                       // only reachable at q==0
                        else atomicAdd(&hist[rr * HSTRIDE + tb], 1);
                    }
                }
            }
        }
        if (c00) atomicAdd(&hist[0], c00);
        __syncthreads();

        // square tile: plain int4 stores (sole writer of this region)
        for (int i = tid; i < 64 * 64; i += 512) {
            const int r  = i >> 6;
            const int c4 = i & 63;
            *(int4*)&joint_t[(size_t)(r0 + r) * NBINS + c4 * 4] =
                *(const int4*)&hist[r * HSTRIDE + c4 * 4];
        }
        // pred marginal rows r0..r0+63: row sums, plain store
        {
            const int r = tid >> 3, s = tid & 7;
            int sum = 0;
            #pragma unroll
            for (int k = 0; k < 32; ++k)
                sum += hist[r * HSTRIDE + s * 32 + ((k + tid) & 31)];
            sum += __shfl_xor(sum, 1);
            sum += __shfl_xor(sum, 2);
            sum += __shfl_xor(sum, 4);
            if (s == 0) pred_g[t * NBINS + r0 + r] = sum;
        }
        // targ marginal cols 0..255: col partial sums, atomic into K1-zeroed base
        {
            const int c = tid >> 1, u = tid & 1;
            int sum = 0;
            #pragma unroll
            for (int r = 0; r < 32; ++r)
                sum += hist[(u * 32 + r) * HSTRIDE + c];
            sum += __shfl_xor(sum, 1);
            if (u == 0 && sum) atomicAdd(&targ_g[t * NBINS + c], sum);
        }
    } else {
        // zero role: out-of-square joint region, coalesced int4 stores
        int4* __restrict__ j4 = (int4*)joint_g;
        const int start = (bid - NHIST) * 512 + tid;
        for (int v = start; v < REGION_TOT; v += NZERO * 512) {
            int4* dst;
            if (v < REGION_A) {                       // rows 256..999, full width
                const int trk2 = v / 186000;
                const int rem  = v - trk2 * 186000;
                dst = j4 + (size_t)trk2 * 250000 + 64000 + rem;
            } else {                                  // rows 0..255, cols 256..999
                const int w2   = v - REGION_A;
                const int trk2 = w2 / 47616;
                const int rem  = w2 - trk2 * 47616;
                const int r    = rem / 186;
                const int c4   = rem - r * 186;
                dst = j4 + (size_t)trk2 * 250000 + r * 250 + 64 + c4;
            }
            *dst = make_int4(0, 0, 0, 0);
        }
    }
}

// ---- K3: apply rare overflow records (joint + both marginals), after all stores ----
__global__ __launch_bounds__(256) void k3_patch(
    const int* __restrict__ ws, int* __restrict__ out)
{
    int* __restrict__ pred_g  = out;
    int* __restrict__ targ_g  = out + TT * NBINS;
    int* __restrict__ joint_g = out + 2 * TT * NBINS;
    for (int b = threadIdx.x; b < K1_BLOCKS; b += 256) {
        const int cnt = ws[WS_CNT_OFF + b];
        for (int k = 0; k < cnt; ++k) {
            const int rec = ws[WS_REC_OFF + b * OV_CAP + k];
            const int trk = rec >> 20;
            const int pb  = (rec >> 10) & 1023;
            const int tb  = rec & 1023;
            atomicAdd(&joint_g[(size_t)trk * NBINS * NBINS + pb * NBINS + tb], 1);
            atomicAdd(&pred_g[trk * NBINS + pb], 1);
            atomicAdd(&targ_g[trk * NBINS + tb], 1);
        }
    }
}

// ---------------- fallback (proven round-2 path) if ws too small ----------------
__global__ __launch_bounds__(256) void fb_zero(int4* __restrict__ p, int n4) {
    const int i = blockIdx.x * 256 + threadIdx.x;
    if (i < n4) p[i] = make_int4(0, 0, 0, 0);
}

__global__ __launch_bounds__(512) void fb_hist(
    const float* __restrict__ yp, const float* __restrict__ yt,
    int* __restrict__ out)
{
    __shared__ int s_h[16 * 1009];
    const int tid = threadIdx.x;
    const int trk = tid & 15;
    const int slot = tid >> 4;
    const int t = blockIdx.y * 16 + trk;

    for (int i = tid; i < 16 * 1009; i += 512) s_h[i] = 0;
    __syncthreads();
    int* __restrict__ reg = &s_h[trk * 1009];
    int* __restrict__ pred_g  = out;
    int* __restrict__ targ_g  = out + TT * NBINS;
    int* __restrict__ joint_g = out + 2 * TT * NBINS;
    int* __restrict__ joint_t = joint_g + (size_t)t * NBINS * NBINS;
    int c00 = 0, cp0 = 0, ct0 = 0;
    const int g0 = blockIdx.x * 128;
    #pragma unroll
    for (int pass = 0; pass < 4; ++pass) {
        const int g = g0 + pass * 32 + slot;
        if (g < NGROUPS) {
            const int b = g / NGPB;
            const int j = g - b * NGPB;
            const size_t base = ((size_t)b * LL + 4 * (size_t)j) * TT + t;
            float xp[8], xt[8];
            #pragma unroll
            for (int k = 0; k < 8; ++k) {
                xp[k] = yp[base + (size_t)k * TT];
                xt[k] = yt[base + (size_t)k * TT];
            }
            #pragma unroll
            for (int r = 0; r < 4; ++r) {
                const float ps = (xp[r]+xp[r+1]+xp[r+2]+xp[r+3]+xp[r+4]) * 0.2f;
                const float ts = (xt[r]+xt[r+1]+xt[r+2]+xt[r+3]+xt[r+4]) * 0.2f;
                if (!(isfinite(ps) && isfinite(ts))) continue;
                const int pb = bin_of(ps);
                const int tb = bin_of(ts);
                if (pb == 0) cp0++;
                else if (pb < 136) atomicAdd(&reg[736 + pb], 1);
                else atomicAdd(&pred_g[t * NBINS + pb], 1);
                if (tb == 0) ct0++;
                else if (tb < 136) atomicAdd(&reg[872 + tb], 1);
                else atomicAdd(&targ_g[t * NBINS + tb], 1);
                if (pb == 0 && tb == 0) c00++;
                else if (pb < 16 && tb < 16) atomicAdd(&reg[pb * 16 + tb], 1);
                else if (pb == 0 && tb < 256) atomicAdd(&reg[256 + tb - 16], 1);
                else if (tb == 0 && pb < 256) atomicAdd(&reg[496 + pb - 16], 1);
                else atomicAdd(&joint_t[pb * NBINS + tb], 1);
            }
        }
    }
    if (c00) atomicAdd(&reg[0],   c00);
    if (cp0) atomicAdd(&reg[736], cp0);
    if (ct0) atomicAdd(&reg[872], ct0);
    __syncthreads();
    const int h0 = blockIdx.y * 16;
    for (int i = tid; i < 16 * 1008; i += 512) {
        const int tr = i / 1008;
        const int sl = i - tr * 1008;
        const int c  = s_h[tr * 1009 + sl];
        if (c == 0) continue;
        const int tg = h0 + tr;
        if (sl < 256) atomicAdd(&joint_g[(size_t)tg * NBINS * NBINS + (sl >> 4) * NBINS + (sl & 15)], c);
        else if (sl < 496) atomicAdd(&joint_g[(size_t)tg * NBINS * NBINS + (sl - 240)], c);
        else if (sl < 736) atomicAdd(&joint_g[(size_t)tg * NBINS * NBINS + (size_t)(sl - 480) * NBINS], c);
        else if (sl < 872) atomicAdd(&pred_g[tg * NBINS + (sl - 736)], c);
        else atomicAdd(&targ_g[tg * NBINS + (sl - 872)], c);
    }
}

extern "C" void kernel_launch(void* const* d_in, const int* in_sizes, int n_in,
                              void* d_out, int out_size, void* d_ws, size_t ws_size,
                              hipStream_t stream) {
    const float* yp = (const float*)d_in[0];
    const float* yt = (const float*)d_in[1];
    int* out = (int*)d_out;

    if (ws_size >= WS_NEEDED) {
        int* ws = (int*)d_ws;
        k1_bin<<<K1_BLOCKS, 512, 0, stream>>>(yp, yt, out, ws);
        k2_main<<<NHIST + NZERO, 512, 64 * HSTRIDE * sizeof(int), stream>>>(ws, out);
        k3_patch<<<1, 256, 0, stream>>>(ws, out);
    } else {
        const int n4 = out_size / 4;
        fb_zero<<<(n4 + 255) / 256, 256, 0, stream>>>((int4*)out, n4);
        dim3 grid((NGROUPS + 127) / 128, 2);
        fb_hist<<<grid, 512, 0, stream>>>(yp, yt, out);
    }
}